// Round 1
// baseline (330.327 us; speedup 1.0000x reference)
//
#include <hip/hip_runtime.h>
#include <math.h>

#define B 8
#define NQ 2048
#define NK 2048
#define XD 2
#define CIN 64
#define COUT 64

constexpr int QBLK   = 64;             // one query per lane
constexpr int NWAVE  = 8;              // waves per block, split keys
constexpr int THREADS = NWAVE * 64;    // 512
constexpr int KCHUNK = NK / NWAVE;     // 256 keys per wave
constexpr int CCH    = 16;             // channel chunk for LDS reduction

__global__ __launch_bounds__(THREADS) void setconv_kernel(
    const float* __restrict__ keys,     // [B][NK][2]
    const float* __restrict__ queries,  // [B][NQ][2]
    const float* __restrict__ values,   // [B][NK][CIN]
    const float* __restrict__ wW,       // [2][2]
    const float* __restrict__ lsp,      // [1]
    const float* __restrict__ dW,       // [1]
    const float* __restrict__ db,       // [1]
    const float* __restrict__ rW,       // [COUT][CIN+1]
    const float* __restrict__ rb,       // [COUT]
    float* __restrict__ out)            // [B][NQ][COUT]
{
    __shared__ float red[NWAVE][QBLK][CCH];   // 32 KiB
    __shared__ float tot[QBLK][CIN + 2];      // 16.5 KiB, [..][64] = esum
    __shared__ float qinfo[QBLK][2];          // inv_esum, density

    const int tid  = threadIdx.x;
    const int wave = tid >> 6;
    const int lane = tid & 63;

    const int bid = blockIdx.x;
    const int b   = bid / (NQ / QBLK);
    const int q0  = (bid % (NQ / QBLK)) * QBLK;
    const int q   = q0 + lane;

    // scalar params (uniform)
    const float W00 = wW[0], W01 = wW[1], W10 = wW[2], W11 = wW[3];
    const float xls = lsp[0] * 0.1f - 1.0f;
    const float sp  = (xls > 20.f) ? xls : log1pf(__expf(xls));
    const float sigma = 1e-5f + sp;
    const float nhis2 = -0.5f / (sigma * sigma);   // -0.5 / sigma^2

    const float qx = queries[(size_t)(b * NQ + q) * XD + 0];
    const float qy = queries[(size_t)(b * NQ + q) * XD + 1];

    float acc[CIN];
    #pragma unroll
    for (int c = 0; c < CIN; ++c) acc[c] = 0.f;
    float esum = 0.f;

    const float* kb = keys   + (size_t)b * NK * XD;
    const float* vb = values + (size_t)b * NK * CIN;
    const int k0 = wave * KCHUNK;

    for (int k = k0; k < k0 + KCHUNK; ++k) {
        const float dx = kb[k * 2 + 0] - qx;
        const float dy = kb[k * 2 + 1] - qy;
        const float e0 = W00 * dx + W01 * dy;
        const float e1 = W10 * dx + W11 * dy;
        const float l  = (e0 * e0 + e1 * e1) * nhis2;
        const float e  = __expf(l);
        esum += e;
        const float4* v4 = reinterpret_cast<const float4*>(vb + (size_t)k * CIN);
        #pragma unroll
        for (int c4 = 0; c4 < CIN / 4; ++c4) {
            const float4 v = v4[c4];
            acc[c4 * 4 + 0] += e * v.x;
            acc[c4 * 4 + 1] += e * v.y;
            acc[c4 * 4 + 2] += e * v.z;
            acc[c4 * 4 + 3] += e * v.w;
        }
    }

    // ---- cross-wave reduction, 4 chunks of 16 channels ----
    for (int ch = 0; ch < CIN / CCH; ++ch) {
        __syncthreads();
        #pragma unroll
        for (int c = 0; c < CCH; ++c) red[wave][lane][c] = acc[ch * CCH + c];
        __syncthreads();
        for (int p = tid; p < QBLK * CCH; p += THREADS) {
            const int qq = p >> 4;
            const int cc = p & 15;
            float s = 0.f;
            #pragma unroll
            for (int w = 0; w < NWAVE; ++w) s += red[w][qq][cc];
            tot[qq][ch * CCH + cc] = s;
        }
    }

    // ---- esum reduction + per-query scalars ----
    __syncthreads();
    red[wave][lane][0] = esum;
    __syncthreads();
    if (tid < QBLK) {
        float s = 0.f;
        #pragma unroll
        for (int w = 0; w < NWAVE; ++w) s += red[w][tid][0];
        tot[tid][CIN] = s;
        // density = sigmoid((-esum * dW + db) * 0.1)
        const float arg = ((-s) * dW[0] + db[0]) * 0.1f;
        qinfo[tid][1] = 1.f / (1.f + __expf(-arg));
        qinfo[tid][0] = 1.f / s;
    }
    __syncthreads();

    // ---- normalize targets by esum ----
    for (int p = tid; p < QBLK * CIN; p += THREADS) {
        const int qq = p >> 6;
        const int cc = p & 63;
        tot[qq][cc] *= qinfo[qq][0];
    }
    __syncthreads();

    // ---- resizer epilogue: out[q][o] = sum_c tot[q][c]*rW[o][c] + dens*rW[o][64] + rb[o]
    {
        const int qq = tid >> 3;                  // 0..63
        const float dens = qinfo[qq][1];
        float* orow = out + (size_t)(b * NQ + q0 + qq) * COUT;
        #pragma unroll
        for (int r = 0; r < 8; ++r) {
            const int o = (tid & 7) + r * 8;
            const float* wrow = rW + o * (CIN + 1);
            float s = rb[o] + dens * wrow[CIN];
            #pragma unroll 8
            for (int c = 0; c < CIN; ++c) s += tot[qq][c] * wrow[c];
            orow[o] = s;
        }
    }
}

extern "C" void kernel_launch(void* const* d_in, const int* in_sizes, int n_in,
                              void* d_out, int out_size, void* d_ws, size_t ws_size,
                              hipStream_t stream) {
    const float* keys    = (const float*)d_in[0];
    const float* queries = (const float*)d_in[1];
    const float* values  = (const float*)d_in[2];
    const float* wW      = (const float*)d_in[3];
    const float* lsp     = (const float*)d_in[4];
    const float* dW      = (const float*)d_in[5];
    const float* db      = (const float*)d_in[6];
    const float* rW      = (const float*)d_in[7];
    const float* rb      = (const float*)d_in[8];
    float* out = (float*)d_out;

    dim3 grid(B * (NQ / QBLK));   // 256 blocks, 1 per CU
    setconv_kernel<<<grid, THREADS, 0, stream>>>(
        keys, queries, values, wW, lsp, dW, db, rW, rb, out);
}